// Round 3
// baseline (764.843 us; speedup 1.0000x reference)
//
#include <hip/hip_runtime.h>
#include <hip/hip_bf16.h>

#define COLS 256          // x columns (= W columns)
#define COLS4 64          // COLS / 4 — one float4 per lane, one row per wave
#define OUTS 128          // W rows = output features
#define WAVES_PER_BLOCK 4
#define GRID_BLOCKS 2048  // 8 blocks/CU * 256 CUs -> 32 waves/CU (max occupancy)

typedef float v4f __attribute__((ext_vector_type(4)));

// Stage 0: zero the 256-float column-sum accumulator (ws is poisoned 0xAA each call)
__global__ void zero_kernel(float* __restrict__ s) {
    s[threadIdx.x] = 0.0f;
}

// Stage 1: s[i] = sum over rows of x[:, i]
// Each wave owns a CONTIGUOUS chunk of rows and streams it sequentially with
// NONTEMPORAL dwordx4 loads (x has zero reuse — skip cache allocation).
// Lane l covers columns 4l..4l+3; one load per lane = 1 KB = one full row.
__global__ __launch_bounds__(256) void colsum_kernel(const float* __restrict__ x,
                                                     float* __restrict__ s,
                                                     int rows) {
    const int lane = threadIdx.x & 63;
    const int wave = threadIdx.x >> 6;                      // 0..3
    const int gwave = blockIdx.x * WAVES_PER_BLOCK + wave;  // global wave id
    const int nwaves = GRID_BLOCKS * WAVES_PER_BLOCK;       // 8192

    const int rpw = (rows + nwaves - 1) / nwaves;           // rows per wave (62)
    int r = gwave * rpw;
    int rend = r + rpw;
    if (rend > rows) rend = rows;

    const v4f* __restrict__ p = (const v4f*)x + (size_t)r * COLS4 + lane;

    v4f a0 = {0.f, 0.f, 0.f, 0.f};
    v4f a1 = {0.f, 0.f, 0.f, 0.f};
    v4f a2 = {0.f, 0.f, 0.f, 0.f};
    v4f a3 = {0.f, 0.f, 0.f, 0.f};

    // 8 rows per iteration: 8 independent nontemporal dwordx4 loads in flight.
    for (; r + 8 <= rend; r += 8, p += 8 * COLS4) {
        v4f v0 = __builtin_nontemporal_load(p + 0 * COLS4);
        v4f v1 = __builtin_nontemporal_load(p + 1 * COLS4);
        v4f v2 = __builtin_nontemporal_load(p + 2 * COLS4);
        v4f v3 = __builtin_nontemporal_load(p + 3 * COLS4);
        v4f v4 = __builtin_nontemporal_load(p + 4 * COLS4);
        v4f v5 = __builtin_nontemporal_load(p + 5 * COLS4);
        v4f v6 = __builtin_nontemporal_load(p + 6 * COLS4);
        v4f v7 = __builtin_nontemporal_load(p + 7 * COLS4);
        a0 += v0; a1 += v1; a2 += v2; a3 += v3;
        a0 += v4; a1 += v5; a2 += v6; a3 += v7;
    }
    for (; r < rend; ++r, p += COLS4) {
        a0 += __builtin_nontemporal_load(p);
    }
    a0 += a1; a2 += a3; a0 += a2;

    // Reduce the block's 4 waves in LDS, then one atomicAdd per column per block.
    __shared__ v4f sm[WAVES_PER_BLOCK][COLS4];
    sm[wave][lane] = a0;
    __syncthreads();
    if (wave == 0) {
        v4f t = sm[0][lane];
        #pragma unroll
        for (int w = 1; w < WAVES_PER_BLOCK; ++w) t += sm[w][lane];
        atomicAdd(&s[lane * 4 + 0], t.x);
        atomicAdd(&s[lane * 4 + 1], t.y);
        atomicAdd(&s[lane * 4 + 2], t.z);
        atomicAdd(&s[lane * 4 + 3], t.w);
    }
}

// Stage 2: h[o] = sum_i s[i] * W[o, i]  (tiny: 128 KB of W, one block)
__global__ void proj_kernel(const float* __restrict__ s,
                            const float* __restrict__ W,
                            float* __restrict__ out) {
    __shared__ float sl[COLS];
    sl[threadIdx.x] = s[threadIdx.x];
    __syncthreads();
    if (threadIdx.x < OUTS) {
        const float4* __restrict__ w4 = (const float4*)(W + threadIdx.x * COLS);
        const float4* __restrict__ s4 = (const float4*)sl;
        float acc = 0.f;
        #pragma unroll
        for (int i = 0; i < COLS4; ++i) {
            float4 w = w4[i];
            float4 v = s4[i];
            acc += w.x * v.x + w.y * v.y + w.z * v.z + w.w * v.w;
        }
        out[threadIdx.x] = acc;
    }
}

extern "C" void kernel_launch(void* const* d_in, const int* in_sizes, int n_in,
                              void* d_out, int out_size, void* d_ws, size_t ws_size,
                              hipStream_t stream) {
    const float* x = (const float*)d_in[0];   // [rows, 256] fp32
    const float* W = (const float*)d_in[1];   // [128, 256] fp32
    float* out = (float*)d_out;               // [128] fp32
    float* s = (float*)d_ws;                  // 256 floats of scratch

    const int rows = in_sizes[0] / COLS;      // 500000

    zero_kernel<<<1, COLS, 0, stream>>>(s);
    colsum_kernel<<<GRID_BLOCKS, 256, 0, stream>>>(x, s, rows);
    proj_kernel<<<1, COLS, 0, stream>>>(s, W, out);
}